// Round 2
// baseline (213.091 us; speedup 1.0000x reference)
//
#include <hip/hip_runtime.h>

typedef unsigned short u16;
typedef unsigned int   u32;
typedef __attribute__((ext_vector_type(8))) short bf16x8;
typedef __attribute__((ext_vector_type(4))) float f32x4;

#define MFMA16(a,b,c) __builtin_amdgcn_mfma_f32_16x16x32_bf16((a),(b),(c),0,0,0)
#define GLD16(gp, lp) __builtin_amdgcn_global_load_lds((const __attribute__((address_space(1))) u32*)(gp), (__attribute__((address_space(3))) u32*)(lp), 16, 0, 0)

#define B_   2
#define NG_  8
#define LS_  512
#define E_   1024
#define NH_  16
#define HD_  64
#define NTOK 8192   // B_*NG_*LS_

__device__ __forceinline__ u16 f2bu(float f){
  u32 u = __builtin_bit_cast(u32, f);
  u32 r = u + 0x7FFFu + ((u >> 16) & 1u);   // RN-even
  return (u16)(r >> 16);
}
__device__ __forceinline__ float b2f(u16 h){
  u32 u = ((u32)h) << 16;
  return __builtin_bit_cast(float, u);
}

// ---------------- fp32 -> bf16 convert (x) ----------------
__global__ __launch_bounds__(256) void k_conv_x(const float* __restrict__ x, u16* __restrict__ xb){
  int i = blockIdx.x * 256 + threadIdx.x;          // 8192*256 = 2,097,152 quads exactly
  float4 v = ((const float4*)x)[i];
  ((ushort4*)xb)[i] = make_ushort4(f2bu(v.x), f2bu(v.y), f2bu(v.z), f2bu(v.w));
}

// ---------------- weight transpose fp32[K][N] -> bf16[N][K] ----------------
__global__ __launch_bounds__(256) void k_transpose(const float* __restrict__ W, u16* __restrict__ WT,
                                                   int Kd, int Nd){
  __shared__ float tile[32][33];
  int tx = threadIdx.x & 31, ty = threadIdx.x >> 5;     // ty 0..7
  int c0 = blockIdx.x * 32, r0 = blockIdx.y * 32;
  #pragma unroll
  for (int i = 0; i < 4; i++)
    tile[ty + i*8][tx] = W[(size_t)(r0 + ty + i*8) * Nd + c0 + tx];
  __syncthreads();
  #pragma unroll
  for (int i = 0; i < 4; i++)
    WT[(size_t)(c0 + ty + i*8) * Kd + r0 + tx] = f2bu(tile[tx][ty + i*8]);
}

// ---------------- RoPE cos/sin table [LS][HD] ----------------
__global__ __launch_bounds__(256) void k_rope_table(float* __restrict__ ct, float* __restrict__ st){
  int i = blockIdx.x * 256 + threadIdx.x;   // 32768
  int s = i >> 6, d = i & 63, j = d & 31;
  float freq = powf(10000.f, -(4.f * (float)j + 1.f) / 64.f);
  float th = (float)s * freq;
  ct[i] = cosf(th);
  st[i] = sinf(th);
}

// ---------------- m97-style bf16 GEMM: C[M,N] = A[M,K] * Bt[N,K]^T ----------------
// OutT = u16 (bf16 store) or float (fp32 store)
template <typename OutT>
__global__ __launch_bounds__(256) void k_gemm_bt(const u16* __restrict__ A, const u16* __restrict__ Bt,
                                                 OutT* __restrict__ C, int M, int N, int K){
  int nbn = N >> 7;
  int bid = blockIdx.x;
  int tm = bid / nbn, tn = bid % nbn;
  int tid = threadIdx.x;
  int w = tid >> 6, l = tid & 63;
  int lr = l & 15, lg = l >> 4;
  int wm = (w >> 1) * 64, wn = (w & 1) * 64;

  __shared__ u16 As[128 * 32];   // linear (global_load_lds requires it)
  __shared__ u16 Bs[128 * 32];

  const u16* Ab = A  + (size_t)(tm * 128) * K;
  const u16* Bb = Bt + (size_t)(tn * 128) * K;

  f32x4 acc[4][4] = {};

  for (int k0 = 0; k0 < K; k0 += 32){
    __syncthreads();
    #pragma unroll
    for (int p = 0; p < 2; p++){
      int c = p * 256 + tid;
      int r = c >> 2, cc = (c & 3) * 8;
      GLD16(Ab + (size_t)r * K + k0 + cc, &As[c * 8]);
      GLD16(Bb + (size_t)r * K + k0 + cc, &Bs[c * 8]);
    }
    __syncthreads();

    bf16x8 a[4], b[4];
    #pragma unroll
    for (int i = 0; i < 4; i++) a[i] = *(const bf16x8*)&As[(wm + i*16 + lr) * 32 + lg * 8];
    #pragma unroll
    for (int j = 0; j < 4; j++) b[j] = *(const bf16x8*)&Bs[(wn + j*16 + lr) * 32 + lg * 8];
    #pragma unroll
    for (int i = 0; i < 4; i++)
      #pragma unroll
      for (int j = 0; j < 4; j++)
        acc[i][j] = MFMA16(a[i], b[j], acc[i][j]);
  }

  #pragma unroll
  for (int i = 0; i < 4; i++)
    #pragma unroll
    for (int j = 0; j < 4; j++)
      #pragma unroll
      for (int r = 0; r < 4; r++){
        int row = tm * 128 + wm + i * 16 + lg * 4 + r;
        int col = tn * 128 + wn + j * 16 + lr;
        float v = acc[i][j][r];
        if constexpr (sizeof(OutT) == 2) C[(size_t)row * N + col] = f2bu(v);
        else                             C[(size_t)row * N + col] = v;
      }
}

// ---------------- RMSNorm + ln_w + RoPE + head split (q scaled by 1/8) ----------------
__global__ __launch_bounds__(256) void k_norm_rope(const u16* __restrict__ qkv, const float* __restrict__ lnw,
                                                   const float* __restrict__ ct, const float* __restrict__ st,
                                                   u16* __restrict__ qh, u16* __restrict__ kh, u16* __restrict__ vh){
  int tok = blockIdx.x;
  int t = threadIdx.x;
  int s = tok & (LS_ - 1);
  int bg = tok >> 9;
  const u16* row = qkv + (size_t)tok * 3072;
  int e0 = t * 4;

  ushort4 q4 = *(const ushort4*)&row[e0];
  ushort4 k4 = *(const ushort4*)&row[1024 + e0];
  ushort4 v4 = *(const ushort4*)&row[2048 + e0];
  float qf[4] = {b2f(q4.x), b2f(q4.y), b2f(q4.z), b2f(q4.w)};
  float kf[4] = {b2f(k4.x), b2f(k4.y), b2f(k4.z), b2f(k4.w)};

  float qss = 0.f, kss = 0.f;
  #pragma unroll
  for (int j = 0; j < 4; j++){ qss += qf[j]*qf[j]; kss += kf[j]*kf[j]; }
  #pragma unroll
  for (int o = 32; o; o >>= 1){ qss += __shfl_down(qss, o); kss += __shfl_down(kss, o); }
  __shared__ float redq[4], redk[4];
  if ((t & 63) == 0){ redq[t >> 6] = qss; redk[t >> 6] = kss; }
  __syncthreads();
  float qsum = redq[0] + redq[1] + redq[2] + redq[3];
  float ksum = redk[0] + redk[1] + redk[2] + redk[3];
  float qr = rsqrtf(qsum * (1.f / 1024.f) + 1e-6f);
  float kr = rsqrtf(ksum * (1.f / 1024.f) + 1e-6f);

  float qn[4], kn[4];
  #pragma unroll
  for (int j = 0; j < 4; j++){
    float wv = lnw[e0 + j];
    qn[j] = qf[j] * qr * wv;
    kn[j] = kf[j] * kr * wv;
  }
  int d0 = e0 & 63, h = e0 >> 6;
  const float* cr = ct + s * 64 + d0;
  const float* sr = st + s * 64 + d0;
  float qo[4], ko[4];
  #pragma unroll
  for (int p = 0; p < 4; p += 2){
    float c0 = cr[p], s0 = sr[p], c1 = cr[p+1], s1 = sr[p+1];
    qo[p]   = qn[p]   * c0 - qn[p+1] * s0;
    qo[p+1] = qn[p+1] * c1 + qn[p]   * s1;
    ko[p]   = kn[p]   * c0 - kn[p+1] * s0;
    ko[p+1] = kn[p+1] * c1 + kn[p]   * s1;
  }
  size_t oidx = (((size_t)bg * NH_ + h) * LS_ + s) * HD_ + d0;
  *(ushort4*)&qh[oidx] = make_ushort4(f2bu(qo[0]*0.125f), f2bu(qo[1]*0.125f), f2bu(qo[2]*0.125f), f2bu(qo[3]*0.125f));
  *(ushort4*)&kh[oidx] = make_ushort4(f2bu(ko[0]), f2bu(ko[1]), f2bu(ko[2]), f2bu(ko[3]));
  *(ushort4*)&vh[oidx] = v4;
}

// ---------------- causal flash attention, one (head, 128-q-block) per workgroup ----------------
__global__ __launch_bounds__(256) void k_attn(const u16* __restrict__ qh, const u16* __restrict__ kh,
                                              const u16* __restrict__ vh, u16* __restrict__ ytok){
  int bid = blockIdx.x;
  int head = bid >> 2, qb = bid & 3;
  int tid = threadIdx.x;
  int w = tid >> 6, l = tid & 63;
  int lr = l & 15, lg = l >> 4;
  const u16* Qp = qh + (size_t)head * LS_ * HD_;
  const u16* Kp = kh + (size_t)head * LS_ * HD_;
  const u16* Vp = vh + (size_t)head * LS_ * HD_;
  int bg = head >> 4, h = head & 15;
  u16* Yb = ytok + (size_t)bg * LS_ * E_ + h * HD_;

  int q0 = qb * 128 + w * 32;   // wave owns 32 q rows
  bf16x8 aq[2][2];
  #pragma unroll
  for (int mi = 0; mi < 2; mi++)
    #pragma unroll
    for (int kk = 0; kk < 2; kk++)
      aq[mi][kk] = *(const bf16x8*)&Qp[(q0 + mi*16 + lr) * 64 + kk * 32 + lg * 8];

  __shared__ u16 Kl[64 * 72];          // K tile [kv][d], padded
  __shared__ u16 Vt[64 * 72];          // V tile transposed [d][kv], padded
  __shared__ u16 Pl[4][32 * 72];       // per-wave P relayout buffer

  f32x4 o[2][4] = {};
  float mrun[2][4], lrun[2][4];
  #pragma unroll
  for (int mi = 0; mi < 2; mi++)
    #pragma unroll
    for (int r = 0; r < 4; r++){ mrun[mi][r] = -1e30f; lrun[mi][r] = 0.f; }

  int nt = (qb + 1) * 2;
  for (int tkv = 0; tkv < nt; tkv++){
    int kv0 = tkv * 64;
    __syncthreads();
    // stage K (copy) and V (transpose) into LDS
    #pragma unroll
    for (int p = 0; p < 2; p++){
      int c = p * 256 + tid;
      int r = c >> 3, c8 = (c & 7) * 8;
      *(bf16x8*)&Kl[r * 72 + c8] = *(const bf16x8*)&Kp[(kv0 + r) * 64 + c8];
      bf16x8 v8 = *(const bf16x8*)&Vp[(kv0 + r) * 64 + c8];
      #pragma unroll
      for (int j = 0; j < 8; j++) Vt[(c8 + j) * 72 + r] = (u16)v8[j];
    }
    __syncthreads();

    if (kv0 <= q0 + 31){     // wave-uniform: this wave has visible keys in tile
      // S = Q K^T  (scale already folded into Q)
      f32x4 sa[2][4] = {};
      #pragma unroll
      for (int nk = 0; nk < 4; nk++){
        bf16x8 b0 = *(const bf16x8*)&Kl[(nk*16 + lr) * 72 + lg * 8];
        bf16x8 b1 = *(const bf16x8*)&Kl[(nk*16 + lr) * 72 + 32 + lg * 8];
        #pragma unroll
        for (int mi = 0; mi < 2; mi++){
          sa[mi][nk] = MFMA16(aq[mi][0], b0, sa[mi][nk]);
          sa[mi][nk] = MFMA16(aq[mi][1], b1, sa[mi][nk]);
        }
      }
      // causal mask (only near diagonal)
      if (kv0 + 63 > q0){
        #pragma unroll
        for (int mi = 0; mi < 2; mi++)
          #pragma unroll
          for (int nk = 0; nk < 4; nk++)
            #pragma unroll
            for (int r = 0; r < 4; r++){
              int qg = q0 + mi*16 + lg*4 + r;
              int kg = kv0 + nk*16 + lr;
              if (kg > qg) sa[mi][nk][r] = -1e30f;
            }
      }
      // online softmax
      #pragma unroll
      for (int mi = 0; mi < 2; mi++){
        #pragma unroll
        for (int r = 0; r < 4; r++){
          float v = fmaxf(fmaxf(sa[mi][0][r], sa[mi][1][r]), fmaxf(sa[mi][2][r], sa[mi][3][r]));
          #pragma unroll
          for (int xm = 1; xm < 16; xm <<= 1) v = fmaxf(v, __shfl_xor(v, xm));
          float mnew = fmaxf(mrun[mi][r], v);
          float alpha = __expf(mrun[mi][r] - mnew);
          mrun[mi][r] = mnew;
          float psum = 0.f;
          #pragma unroll
          for (int nk = 0; nk < 4; nk++){
            float pv = __expf(sa[mi][nk][r] - mnew);
            sa[mi][nk][r] = pv;
            psum += pv;
          }
          #pragma unroll
          for (int xm = 1; xm < 16; xm <<= 1) psum += __shfl_xor(psum, xm);
          lrun[mi][r] = lrun[mi][r] * alpha + psum;
          #pragma unroll
          for (int nd = 0; nd < 4; nd++) o[mi][nd][r] *= alpha;
        }
        // P (C-layout) -> LDS for A-layout reads; per-wave buffer, in-wave DS order suffices
        #pragma unroll
        for (int nk = 0; nk < 4; nk++)
          #pragma unroll
          for (int r = 0; r < 4; r++)
            Pl[w][(mi*16 + lg*4 + r) * 72 + nk*16 + lr] = f2bu(sa[mi][nk][r]);
      }
      // O += P @ V
      #pragma unroll
      for (int kk = 0; kk < 2; kk++){
        bf16x8 ap[2];
        #pragma unroll
        for (int mi = 0; mi < 2; mi++)
          ap[mi] = *(const bf16x8*)&Pl[w][(mi*16 + lr) * 72 + kk * 32 + lg * 8];
        #pragma unroll
        for (int nd = 0; nd < 4; nd++){
          bf16x8 bv = *(const bf16x8*)&Vt[(nd*16 + lr) * 72 + kk * 32 + lg * 8];
          #pragma unroll
          for (int mi = 0; mi < 2; mi++)
            o[mi][nd] = MFMA16(ap[mi], bv, o[mi][nd]);
        }
      }
    }
  }
  // finalize: divide by l, store to token layout
  #pragma unroll
  for (int mi = 0; mi < 2; mi++){
    float inv[4];
    #pragma unroll
    for (int r = 0; r < 4; r++) inv[r] = 1.f / lrun[mi][r];
    #pragma unroll
    for (int nd = 0; nd < 4; nd++)
      #pragma unroll
      for (int r = 0; r < 4; r++){
        int qg = q0 + mi*16 + lg*4 + r;
        Yb[(size_t)qg * E_ + nd*16 + lr] = f2bu(o[mi][nd][r] * inv[r]);
      }
  }
}

extern "C" void kernel_launch(void* const* d_in, const int* in_sizes, int n_in,
                              void* d_out, int out_size, void* d_ws, size_t ws_size,
                              hipStream_t stream){
  const float* x     = (const float*)d_in[0];
  const float* Wqkv  = (const float*)d_in[1];
  const float* lnw   = (const float*)d_in[2];
  const float* Wproj = (const float*)d_in[3];
  float* out = (float*)d_out;   // reference output dtype is float32

  u16* p = (u16*)d_ws;
  u16* xb     = p; p += (size_t)NTOK * E_;        // 16.8MB, reused as ytok after GEMM1
  u16* wqkvT  = p; p += (size_t)3 * E_ * E_;      // [3072][1024] bf16
  u16* wprojT = p; p += (size_t)E_ * E_;          // [1024][1024] bf16
  u16* qkv    = p; p += (size_t)NTOK * 3 * E_;    // 50.3MB
  u16* qhp    = p; p += (size_t)NTOK * E_;
  u16* khp    = p; p += (size_t)NTOK * E_;
  u16* vhp    = p; p += (size_t)NTOK * E_;
  float* ct = (float*)p;
  float* st = ct + LS_ * HD_;

  k_conv_x<<<8192, 256, 0, stream>>>(x, xb);
  k_transpose<<<dim3(96, 32), 256, 0, stream>>>(Wqkv, wqkvT, 1024, 3072);
  k_transpose<<<dim3(32, 32), 256, 0, stream>>>(Wproj, wprojT, 1024, 1024);
  k_rope_table<<<128, 256, 0, stream>>>(ct, st);
  k_gemm_bt<u16><<<64 * 24, 256, 0, stream>>>(xb, wqkvT, qkv, NTOK, 3 * E_, E_);
  k_norm_rope<<<NTOK, 256, 0, stream>>>(qkv, lnw, ct, st, qhp, khp, vhp);
  k_attn<<<1024, 256, 0, stream>>>(qhp, khp, vhp, xb);           // xb now = y_tok
  k_gemm_bt<float><<<64 * 8, 256, 0, stream>>>(xb, wprojT, out, NTOK, E_, E_);
}